// Round 4
// baseline (156.404 us; speedup 1.0000x reference)
//
#include <hip/hip_runtime.h>
#include <hip/hip_cooperative_groups.h>
#include <math.h>

namespace cg = cooperative_groups;

// B=64, IN=1024, output_size=1024, D_MODEL=64, X_KS=Y_KS=32, HIDDEN=256
constexpr int B    = 64;
constexpr int IN   = 1024;
constexpr int OUTN = 1024;
constexpr int H    = 256;

#define LN10000 9.210340371976184f
#define TWO_LOG2E 2.8853900817779268f   // 2*log2(e); exp(2x) = exp2(x*TWO_LOG2E)

__device__ __forceinline__ float fast_tanh(float x) {
    // tanh(x) = 1 - 2/(e^{2x}+1); error budget is huge (absmax thresh 1.47)
    x = fminf(fmaxf(x, -15.0f), 15.0f);
    float e = __builtin_amdgcn_exp2f(x * TWO_LOG2E);
    return 1.0f - 2.0f * __builtin_amdgcn_rcpf(e + 1.0f);
}

// --------------------------- shared-memory layout ---------------------------
struct SmemA {                    // phase A (k1)
    float xs[1024];
    float w1s[2048];              // W1[128+k][c0+cl]
    float As[2048];               // b1 + pe_x@W1 + Q
    float red[1024];
};
struct SmemB {                    // phase B (k2)
    float vsh[2048];
    float hpe[256];
    float osp[1024];
    float os[256];
    float hbs[2048];
    float Wb2s[8192];
    float bp[1024];
    float Ssh[8];
};
union Smem { SmemA a; SmemB b; };  // 59.4 KB -> 1 block/CU, 16 waves

// ---------------------------------------------------------------------------
// Tables: 24 blocks x 1024 threads, one output each.
// idx = bid*1024+tid -> table = idx>>13 (PA,PY,HPE), p = (idx>>8)&31, c = idx&255.
// Wave-uniform (table,p); lane L holds pe(p)[L] via one sin/cos, dot via shfl.
//   PA[p][c]  = b1[c]  + pe(p) . W1[0:64][c]
//   PY[p][c]  =          pe(p) . W1[64:128][c]
//   HPE[t][c] = bb1[c] + pe(t) . Wb1[32:96][c]
// ---------------------------------------------------------------------------
__device__ __forceinline__ void tables_body(int bid, int tid,
                                            const float* __restrict__ W1,
                                            const float* __restrict__ b1,
                                            const float* __restrict__ Wb1,
                                            const float* __restrict__ bb1,
                                            float* __restrict__ PA,
                                            float* __restrict__ PY,
                                            float* __restrict__ HPE) {
    const int idx = bid * 1024 + tid;              // < 24576
    const int table = idx >> 13;
    const int p = (idx >> 8) & 31, c = idx & 255;
    const int L = tid & 63;
    float freq = expf(-(2.0f * (float)(L >> 1) / 64.0f) * LN10000);
    float a = (float)p * freq;
    float pel = (L & 1) ? cosf(a) : sinf(a);       // lane L = pe(p)[L]
    const float* src; float acc; float* dst;
    if (table == 0)      { src = W1;           acc = b1[c];  dst = PA;  }
    else if (table == 1) { src = W1 + 64 * H;  acc = 0.0f;   dst = PY;  }
    else                 { src = Wb1 + 32 * H; acc = bb1[c]; dst = HPE; }
    #pragma unroll 16
    for (int d = 0; d < 64; ++d)
        acc += __shfl(pel, d, 64) * src[d * H + c];   // coalesced 1KB/row
    dst[p * H + c] = acc;
}

// ---------------------------------------------------------------------------
// K1 split into prefix (table-independent) and finish (needs PA/PY).
// block = (b = bid>>2, cq = bid&3); thread = (jg = tid>>6 in [0,16), cl = tid&63).
// ---------------------------------------------------------------------------
__device__ __forceinline__ void k1_prefix(int bid, int tid,
                                          const float* __restrict__ x,
                                          const float* __restrict__ W1,
                                          SmemA& sa, float& acc0, float& acc1,
                                          float* __restrict__ S) {
    const int b = bid >> 2, cq = bid & 3, c0 = cq * 64;
    const int cl = tid & 63, jg = tid >> 6, p0 = jg * 2;

    sa.xs[tid] = x[b * IN + tid];
    #pragma unroll
    for (int i = 0; i < 2; ++i) {                 // w1s[k][cl] = W1[128+k][c0+cl]
        const int idx = i * 1024 + tid;
        const int p = idx >> 6, c = idx & 63;
        sa.w1s[idx] = W1[(128 + p) * H + c0 + c];
    }
    __syncthreads();

    if (cq == 0 && tid < 64) {                    // S[b]: one wave, shuffle reduce
        float s = 0.0f;
        #pragma unroll
        for (int i = 0; i < 16; ++i) s += sa.xs[tid + i * 64];
        #pragma unroll
        for (int off = 32; off > 0; off >>= 1) s += __shfl_xor(s, off, 64);
        if (tid == 0) S[b] = s;
    }

    // Q: acc_r = sum_k x[b][(p0+r)*32+k] * W1[128+k][c]
    acc0 = 0.0f; acc1 = 0.0f;
    #pragma unroll 8
    for (int k = 0; k < 32; ++k) {
        const float w = sa.w1s[k * 64 + cl];      // stride-1, 2-way free
        acc0 += sa.xs[p0 * 32 + k] * w;           // broadcast read: free
        acc1 += sa.xs[(p0 + 1) * 32 + k] * w;
    }
}

__device__ __forceinline__ void k1_finish(int bid, int tid,
                                          const float* __restrict__ PA,
                                          const float* __restrict__ PY,
                                          SmemA& sa, float acc0, float acc1,
                                          float* __restrict__ v) {
    const int b = bid >> 2, cq = bid & 3, c0 = cq * 64;
    const int cl = tid & 63, jg = tid >> 6, p0 = jg * 2;

    acc0 += PA[p0 * H + c0 + cl];                 // coalesced (p0 wave-uniform)
    acc1 += PA[(p0 + 1) * H + c0 + cl];
    const float py0 = PY[p0 * H + c0 + cl];
    const float py1 = PY[(p0 + 1) * H + c0 + cl];
    sa.As[p0 * 64 + cl]       = acc0;
    sa.As[(p0 + 1) * 64 + cl] = acc1;
    __syncthreads();

    float Areg[32];
    #pragma unroll
    for (int jx = 0; jx < 32; ++jx) Areg[jx] = sa.As[jx * 64 + cl];  // 2-way free
    float acc = 0.0f;
    #pragma unroll
    for (int r = 0; r < 2; ++r) {
        const int jy = p0 + r;
        const float pyv = r ? py1 : py0;
        const float4* xr = (const float4*)(sa.xs + jy * 32);   // broadcast reads
        #pragma unroll
        for (int q8 = 0; q8 < 8; ++q8) {
            float4 xv = xr[q8];
            acc += xv.x * fast_tanh(Areg[q8 * 4 + 0] + pyv);
            acc += xv.y * fast_tanh(Areg[q8 * 4 + 1] + pyv);
            acc += xv.z * fast_tanh(Areg[q8 * 4 + 2] + pyv);
            acc += xv.w * fast_tanh(Areg[q8 * 4 + 3] + pyv);
        }
    }
    sa.red[tid] = acc;                            // layout jg*64 + cl == tid
    __syncthreads();
    if (tid < 64) {
        float s = 0.0f;
        #pragma unroll
        for (int g = 0; g < 16; ++g) s += sa.red[g * 64 + tid];
        v[b * H + c0 + tid] = s;
    }
}

// ---------------------------------------------------------------------------
// K2 body (round-2 proven): block = (og = bid&31, bg = bid>>5), 1024 threads.
// h = tid>>8 in [0,4): 4-way c-split of phases 1/3; Wb2 staged; HPE loaded.
// ---------------------------------------------------------------------------
__device__ __forceinline__ void k2_body(int bid, int tid,
                                        const float* __restrict__ v,
                                        const float* __restrict__ S,
                                        const float* __restrict__ W2,
                                        const float* __restrict__ b2,
                                        const float* __restrict__ Wb1,
                                        const float* __restrict__ HPE,
                                        const float* __restrict__ Wb2,
                                        const float* __restrict__ bb2,
                                        SmemB& sb, float* __restrict__ out) {
    const int og = bid & 31, bg = bid >> 5, b0 = bg * 8;
    const int h = tid >> 8, u = tid & 255, bl = u >> 5, ol = u & 31;

    ((float2*)sb.vsh)[tid] = ((const float2*)(v + b0 * H))[tid];
    #pragma unroll
    for (int i = 0; i < 2; ++i)
        ((float4*)sb.Wb2s)[i * 1024 + tid] = ((const float4*)Wb2)[i * 1024 + tid];
    if (tid < 256) sb.hpe[tid] = HPE[og * H + tid];
    if (tid < 8) sb.Ssh[tid] = S[b0 + tid];
    __syncthreads();

    const int o = og * 32 + ol;
    // phase 1: os[bl][ol] = S*b2 + v[b]·W2[:,o]  (c-quarter per h)
    {
        float acc = (h == 0) ? sb.Ssh[bl] * b2[o] : 0.0f;
        const float4* vr = (const float4*)(sb.vsh + bl * H + h * 64);
        #pragma unroll
        for (int c4 = 0; c4 < 16; ++c4) {
            float4 v4 = vr[c4];
            const int c = h * 64 + c4 * 4;
            acc += v4.x * W2[(c + 0) * OUTN + o];
            acc += v4.y * W2[(c + 1) * OUTN + o];
            acc += v4.z * W2[(c + 2) * OUTN + o];
            acc += v4.w * W2[(c + 3) * OUTN + o];
        }
        sb.osp[h * 256 + u] = acc;
    }
    __syncthreads();
    if (tid < 256)
        sb.os[tid] = sb.osp[tid] + sb.osp[256 + tid] + sb.osp[512 + tid] + sb.osp[768 + tid];
    __syncthreads();
    // phase 2: hb[bl][c] = tanh(hpe[c] + os[bl]·Wb1[:,c]); c = h*64 + {0,32} + ol
    {
        float a0 = sb.hpe[h * 64 + ol];
        float a1 = sb.hpe[h * 64 + 32 + ol];
        const float4* osr = (const float4*)(sb.os + bl * 32);   // broadcast
        #pragma unroll
        for (int k4 = 0; k4 < 8; ++k4) {
            float4 o4 = osr[k4];
            const float* wr = Wb1 + (k4 * 4) * H + h * 64 + ol;
            a0 += o4.x * wr[0];         a1 += o4.x * wr[32];
            a0 += o4.y * wr[H];         a1 += o4.y * wr[H + 32];
            a0 += o4.z * wr[2 * H];     a1 += o4.z * wr[2 * H + 32];
            a0 += o4.w * wr[3 * H];     a1 += o4.w * wr[3 * H + 32];
        }
        sb.hbs[bl * H + h * 64 + ol]      = fast_tanh(a0);
        sb.hbs[bl * H + h * 64 + 32 + ol] = fast_tanh(a1);
    }
    __syncthreads();
    // phase 3: bias = bb2 + hb·Wb2  (c-quarter per h, Wb2 from LDS)
    {
        float bias = (h == 0) ? bb2[ol] : 0.0f;
        const float4* hr = (const float4*)(sb.hbs + bl * H + h * 64);
        #pragma unroll
        for (int c4 = 0; c4 < 16; ++c4) {
            float4 h4 = hr[c4];
            const int c = h * 64 + c4 * 4;
            bias += h4.x * sb.Wb2s[(c + 0) * 32 + ol];
            bias += h4.y * sb.Wb2s[(c + 1) * 32 + ol];
            bias += h4.z * sb.Wb2s[(c + 2) * 32 + ol];
            bias += h4.w * sb.Wb2s[(c + 3) * 32 + ol];
        }
        sb.bp[h * 256 + u] = bias;
    }
    __syncthreads();
    if (tid < 256) {
        out[(b0 + (tid >> 5)) * OUTN + og * 32 + (tid & 31)] =
            sb.os[tid] + sb.bp[tid] + sb.bp[256 + tid] + sb.bp[512 + tid] + sb.bp[768 + tid];
    }
}

// ---------------------------------------------------------------------------
// Fused cooperative kernel: 256 blocks x 1024 threads, 1 block/CU.
// tables (blocks 0..23) || k1 prefix -> grid.sync -> k1 finish -> grid.sync -> k2
// ---------------------------------------------------------------------------
__global__ void __launch_bounds__(1024, 4)
fused_all(const float* __restrict__ x,  const float* __restrict__ W1,
          const float* __restrict__ b1, const float* __restrict__ W2,
          const float* __restrict__ b2, const float* __restrict__ Wb1,
          const float* __restrict__ bb1,const float* __restrict__ Wb2,
          const float* __restrict__ bb2,float* __restrict__ out,
          float* __restrict__ v, float* __restrict__ S,
          float* __restrict__ PA, float* __restrict__ PY, float* __restrict__ HPE) {
    __shared__ Smem sm;
    const int bid = blockIdx.x, tid = threadIdx.x;
    cg::grid_group grid = cg::this_grid();

    if (bid < 24) tables_body(bid, tid, W1, b1, Wb1, bb1, PA, PY, HPE);

    float acc0, acc1;
    k1_prefix(bid, tid, x, W1, sm.a, acc0, acc1, S);

    grid.sync();                                  // tables ready

    k1_finish(bid, tid, PA, PY, sm.a, acc0, acc1, v);

    grid.sync();                                  // v, S ready

    k2_body(bid, tid, v, S, W2, b2, Wb1, HPE, Wb2, bb2, sm.b, out);
}

// --------------------------- fallback (3 launches) --------------------------
__global__ void __launch_bounds__(1024) k0_t(const float* __restrict__ W1,
                                             const float* __restrict__ b1,
                                             const float* __restrict__ Wb1,
                                             const float* __restrict__ bb1,
                                             float* __restrict__ PA,
                                             float* __restrict__ PY,
                                             float* __restrict__ HPE) {
    tables_body(blockIdx.x, threadIdx.x, W1, b1, Wb1, bb1, PA, PY, HPE);
}

__global__ void __launch_bounds__(1024, 4) k1_s(const float* __restrict__ x,
                                                const float* __restrict__ W1,
                                                const float* __restrict__ PA,
                                                const float* __restrict__ PY,
                                                float* __restrict__ v,
                                                float* __restrict__ S) {
    __shared__ SmemA sa;
    float acc0, acc1;
    k1_prefix(blockIdx.x, threadIdx.x, x, W1, sa, acc0, acc1, S);
    k1_finish(blockIdx.x, threadIdx.x, PA, PY, sa, acc0, acc1, v);
}

__global__ void __launch_bounds__(1024) k2_s(const float* __restrict__ v,
                                             const float* __restrict__ S,
                                             const float* __restrict__ W2,
                                             const float* __restrict__ b2,
                                             const float* __restrict__ Wb1,
                                             const float* __restrict__ HPE,
                                             const float* __restrict__ Wb2,
                                             const float* __restrict__ bb2,
                                             float* __restrict__ out) {
    __shared__ SmemB sb;
    k2_body(blockIdx.x, threadIdx.x, v, S, W2, b2, Wb1, HPE, Wb2, bb2, sb, out);
}

// ---------------------------------------------------------------------------
extern "C" void kernel_launch(void* const* d_in, const int* in_sizes, int n_in,
                              void* d_out, int out_size, void* d_ws, size_t ws_size,
                              hipStream_t stream) {
    const float* x   = (const float*)d_in[0];
    // d_in[1] = output_size (fixed 1024)
    const float* W1  = (const float*)d_in[2];
    const float* b1  = (const float*)d_in[3];
    const float* W2  = (const float*)d_in[4];
    const float* b2  = (const float*)d_in[5];
    const float* Wb1 = (const float*)d_in[6];
    const float* bb1 = (const float*)d_in[7];
    const float* Wb2 = (const float*)d_in[8];
    const float* bb2 = (const float*)d_in[9];
    float* out = (float*)d_out;

    float* v   = (float*)d_ws;       // B*H
    float* S   = v + B * H;          // B
    float* PA  = S + B;              // 32*H
    float* PY  = PA + 32 * H;        // 32*H
    float* HPE = PY + 32 * H;        // 32*H  (total 164 KB; ws is 256 MiB)

    void* args[] = { (void*)&x, (void*)&W1, (void*)&b1, (void*)&W2, (void*)&b2,
                     (void*)&Wb1, (void*)&bb1, (void*)&Wb2, (void*)&bb2,
                     (void*)&out, (void*)&v, (void*)&S,
                     (void*)&PA, (void*)&PY, (void*)&HPE };
    hipError_t e = hipLaunchCooperativeKernel((const void*)fused_all,
                                              dim3(256), dim3(1024),
                                              args, 0, stream);
    if (e != hipSuccess) {           // fallback: proven 3-kernel path
        hipLaunchKernelGGL(k0_t, dim3(24),    dim3(1024), 0, stream,
                           W1, b1, Wb1, bb1, PA, PY, HPE);
        hipLaunchKernelGGL(k1_s, dim3(B * 4), dim3(1024), 0, stream,
                           x, W1, PA, PY, v, S);
        hipLaunchKernelGGL(k2_s, dim3(256),   dim3(1024), 0, stream,
                           v, S, W2, b2, Wb1, HPE, Wb2, bb2, out);
    }
}

// Round 5
// 89.150 us; speedup vs baseline: 1.7544x; 1.7544x over previous
//
#include <hip/hip_runtime.h>
#include <math.h>

// B=64, IN=1024, output_size=1024, D_MODEL=64, X_KS=Y_KS=32, HIDDEN=256
constexpr int B    = 64;
constexpr int IN   = 1024;
constexpr int OUTN = 1024;
constexpr int H    = 256;

#define LN10000 9.210340371976184f
#define TWO_LOG2E 2.8853900817779268f   // 2*log2(e); exp(2x) = exp2(x*TWO_LOG2E)

__device__ __forceinline__ float fast_tanh(float x) {
    // tanh(x) = 1 - 2/(e^{2x}+1); error budget is huge (absmax thresh 1.47)
    x = fminf(fmaxf(x, -15.0f), 15.0f);
    float e = __builtin_amdgcn_exp2f(x * TWO_LOG2E);
    return 1.0f - 2.0f * __builtin_amdgcn_rcpf(e + 1.0f);
}

// ---------------------------------------------------------------------------
// K0: 96 blocks = (table in [0,3), p in [0,32)), 256 threads = c.
//   PA[p][c]  = b1[c]  + sum_d pe(p)[d] * W1[d][c]       (pe_x rows 0..63)
//   PY[p][c]  =          sum_d pe(p)[d] * W1[64+d][c]    (pe_y rows 64..127)
//   HPE[t][c] = bb1[c] + sum_d pe(t)[d] * Wb1[32+d][c]   (bias-hypernet pe)
// All trig + all b-redundant matmul work lives here, off the serial path of
// the consumers. Proven pattern (round-2 k0, widened to 3 tables).
// ---------------------------------------------------------------------------
__global__ void __launch_bounds__(256) k0_tables(const float* __restrict__ W1,
                                                 const float* __restrict__ b1,
                                                 const float* __restrict__ Wb1,
                                                 const float* __restrict__ bb1,
                                                 float* __restrict__ PA,
                                                 float* __restrict__ PY,
                                                 float* __restrict__ HPE) {
    __shared__ float pe[64];
    const int blk = blockIdx.x, tid = threadIdx.x;
    const int p = blk & 31, table = blk >> 5;
    if (tid < 32) {
        float freq = expf(-(2.0f * (float)tid / 64.0f) * LN10000);
        float a = (float)p * freq;
        pe[2 * tid]     = sinf(a);
        pe[2 * tid + 1] = cosf(a);
    }
    __syncthreads();
    const float* src; float acc; float* dst;
    if (table == 0)      { src = W1;           acc = b1[tid];  dst = PA;  }
    else if (table == 1) { src = W1 + 64 * H;  acc = 0.0f;     dst = PY;  }
    else                 { src = Wb1 + 32 * H; acc = bb1[tid]; dst = HPE; }
    #pragma unroll 16
    for (int d = 0; d < 64; ++d) acc += pe[d] * src[d * H + tid];   // coalesced 1KB/row
    dst[p * H + tid] = acc;
}

// ---------------------------------------------------------------------------
// K1: 256 blocks = (b, cq), 1024 threads (16 waves -> 4/SIMD).
// Round-2 proven body. Q-loop xs reads vectorized to float4 broadcasts
// (64 ds_read_b32 -> 16 ds_read_b128, wave-uniform => conflict-free);
// PA/PY register loads issued before the staging barrier to hide L2 latency.
// ---------------------------------------------------------------------------
__global__ void __launch_bounds__(1024, 4) k1_v(const float* __restrict__ x,
                                                const float* __restrict__ W1,
                                                const float* __restrict__ PA,
                                                const float* __restrict__ PY,
                                                float* __restrict__ v,
                                                float* __restrict__ S) {
    __shared__ float xs[1024];
    __shared__ float w1s[2048];   // w1s[k][cl] = W1[128+k][c0+cl]
    __shared__ float As[2048];    // b1 + pe_x@W1 + Q
    __shared__ float red[1024];
    const int blk = blockIdx.x, tid = threadIdx.x;
    const int b = blk >> 2, cq = blk & 3, c0 = cq * 64;
    const int cl = tid & 63, jg = tid >> 6, p0 = jg * 2;

    xs[tid] = x[b * IN + tid];
    #pragma unroll
    for (int i = 0; i < 2; ++i) {                 // coalesced: consec tid -> consec c
        const int idx = i * 1024 + tid;
        const int p = idx >> 6, c = idx & 63;
        w1s[idx] = W1[(128 + p) * H + c0 + c];
    }
    // issue table loads early: L2 latency hides under the staging barrier
    float acc0 = PA[p0 * H + c0 + cl];            // p0 wave-uniform -> coalesced
    float acc1 = PA[(p0 + 1) * H + c0 + cl];
    const float py0 = PY[p0 * H + c0 + cl];
    const float py1 = PY[(p0 + 1) * H + c0 + cl];
    __syncthreads();

    if (cq == 0 && tid < 64) {                    // S[b]: one wave, shuffle reduce
        float s = 0.0f;
        #pragma unroll
        for (int i = 0; i < 16; ++i) s += xs[tid + i * 64];
        #pragma unroll
        for (int off = 32; off > 0; off >>= 1) s += __shfl_xor(s, off, 64);
        if (tid == 0) S[b] = s;
    }

    // Q: acc_r += sum_k x[b][(p0+r)*32+k] * W1[128+k][c]; xs as b128 broadcasts
    {
        const float4* x0 = (const float4*)(xs + p0 * 32);
        const float4* x1 = (const float4*)(xs + (p0 + 1) * 32);
        #pragma unroll
        for (int q8 = 0; q8 < 8; ++q8) {
            float4 a4 = x0[q8], b4 = x1[q8];
            const float w0 = w1s[(q8 * 4 + 0) * 64 + cl];
            const float w1 = w1s[(q8 * 4 + 1) * 64 + cl];
            const float w2 = w1s[(q8 * 4 + 2) * 64 + cl];
            const float w3 = w1s[(q8 * 4 + 3) * 64 + cl];
            acc0 += a4.x * w0; acc1 += b4.x * w0;
            acc0 += a4.y * w1; acc1 += b4.y * w1;
            acc0 += a4.z * w2; acc1 += b4.z * w2;
            acc0 += a4.w * w3; acc1 += b4.w * w3;
        }
    }
    As[p0 * 64 + cl]       = acc0;
    As[(p0 + 1) * 64 + cl] = acc1;
    __syncthreads();

    float Areg[32];
    #pragma unroll
    for (int jx = 0; jx < 32; ++jx) Areg[jx] = As[jx * 64 + cl];  // 2-way free
    float acc = 0.0f;
    #pragma unroll
    for (int r = 0; r < 2; ++r) {
        const float pyv = r ? py1 : py0;
        const float4* xr = (const float4*)(xs + (p0 + r) * 32);   // broadcast
        #pragma unroll
        for (int q8 = 0; q8 < 8; ++q8) {
            float4 xv = xr[q8];
            acc += xv.x * fast_tanh(Areg[q8 * 4 + 0] + pyv);
            acc += xv.y * fast_tanh(Areg[q8 * 4 + 1] + pyv);
            acc += xv.z * fast_tanh(Areg[q8 * 4 + 2] + pyv);
            acc += xv.w * fast_tanh(Areg[q8 * 4 + 3] + pyv);
        }
    }
    red[tid] = acc;                               // layout jg*64 + cl == tid
    __syncthreads();
    if (tid < 64) {
        float s = 0.0f;
        #pragma unroll
        for (int g = 0; g < 16; ++g) s += red[g * 64 + tid];
        v[b * H + c0 + tid] = s;
    }
}

// ---------------------------------------------------------------------------
// K2: 256 blocks = (og, bg), 1024 threads (16 waves -> 4/SIMD).
// Round-2 proven body; hpe now a single coalesced load from the hoisted HPE
// table (was: serial 64-iteration global dot before phase 1 could start).
// h = tid>>8 in [0,4): 4-way c-split of phases 1/3; Wb2 staged in LDS.
// ---------------------------------------------------------------------------
__global__ void __launch_bounds__(1024) k2_out(const float* __restrict__ v,
                                               const float* __restrict__ S,
                                               const float* __restrict__ W2,
                                               const float* __restrict__ b2,
                                               const float* __restrict__ Wb1,
                                               const float* __restrict__ HPE,
                                               const float* __restrict__ Wb2,
                                               const float* __restrict__ bb2,
                                               float* __restrict__ out) {
    __shared__ float vsh[2048];      // v rows for 8 samples
    __shared__ float hpe[256];       // HPE[og][:]
    __shared__ float osp[1024];      // phase-1 partials (4 quarters)
    __shared__ float os[256];        // out-tile (pre-bias)
    __shared__ float hbs[2048];      // tanh activations
    __shared__ float Wb2s[8192];     // staged Wb2
    __shared__ float bp[1024];       // phase-3 partials
    __shared__ float Ssh[8];
    const int blk = blockIdx.x, tid = threadIdx.x;
    const int og = blk & 31, bg = blk >> 5, b0 = bg * 8;
    const int h = tid >> 8, u = tid & 255, bl = u >> 5, ol = u & 31;

    ((float2*)vsh)[tid] = ((const float2*)(v + b0 * H))[tid];
    #pragma unroll
    for (int i = 0; i < 2; ++i)
        ((float4*)Wb2s)[i * 1024 + tid] = ((const float4*)Wb2)[i * 1024 + tid];
    if (tid < 256) hpe[tid] = HPE[og * H + tid];   // one coalesced 1KB load
    if (tid < 8) Ssh[tid] = S[b0 + tid];
    __syncthreads();

    const int o = og * 32 + ol;
    // phase 1: os[bl][ol] = S*b2 + v[b]·W2[:,o]  (c-quarter per h)
    {
        float acc = (h == 0) ? Ssh[bl] * b2[o] : 0.0f;
        const float4* vr = (const float4*)(vsh + bl * H + h * 64);
        #pragma unroll
        for (int c4 = 0; c4 < 16; ++c4) {
            float4 v4 = vr[c4];
            const int c = h * 64 + c4 * 4;
            acc += v4.x * W2[(c + 0) * OUTN + o];
            acc += v4.y * W2[(c + 1) * OUTN + o];
            acc += v4.z * W2[(c + 2) * OUTN + o];
            acc += v4.w * W2[(c + 3) * OUTN + o];
        }
        osp[h * 256 + u] = acc;
    }
    __syncthreads();
    if (tid < 256)
        os[tid] = osp[tid] + osp[256 + tid] + osp[512 + tid] + osp[768 + tid];
    __syncthreads();
    // phase 2: hb[bl][c] = tanh(hpe[c] + os[bl]·Wb1[:,c]); c = h*64 + {0,32} + ol
    {
        float a0 = hpe[h * 64 + ol];
        float a1 = hpe[h * 64 + 32 + ol];
        const float4* osr = (const float4*)(os + bl * 32);   // broadcast reads
        #pragma unroll
        for (int k4 = 0; k4 < 8; ++k4) {
            float4 o4 = osr[k4];
            const float* wr = Wb1 + (k4 * 4) * H + h * 64 + ol;
            a0 += o4.x * wr[0];         a1 += o4.x * wr[32];
            a0 += o4.y * wr[H];         a1 += o4.y * wr[H + 32];
            a0 += o4.z * wr[2 * H];     a1 += o4.z * wr[2 * H + 32];
            a0 += o4.w * wr[3 * H];     a1 += o4.w * wr[3 * H + 32];
        }
        hbs[bl * H + h * 64 + ol]      = fast_tanh(a0);
        hbs[bl * H + h * 64 + 32 + ol] = fast_tanh(a1);
    }
    __syncthreads();
    // phase 3: bias = bb2 + hb·Wb2  (c-quarter per h, Wb2 from LDS)
    {
        float bias = (h == 0) ? bb2[ol] : 0.0f;
        const float4* hr = (const float4*)(hbs + bl * H + h * 64);
        #pragma unroll
        for (int c4 = 0; c4 < 16; ++c4) {
            float4 h4 = hr[c4];
            const int c = h * 64 + c4 * 4;
            bias += h4.x * Wb2s[(c + 0) * 32 + ol];
            bias += h4.y * Wb2s[(c + 1) * 32 + ol];
            bias += h4.z * Wb2s[(c + 2) * 32 + ol];
            bias += h4.w * Wb2s[(c + 3) * 32 + ol];
        }
        bp[h * 256 + u] = bias;
    }
    __syncthreads();
    if (tid < 256) {
        out[(b0 + (tid >> 5)) * OUTN + og * 32 + (tid & 31)] =
            os[tid] + bp[tid] + bp[256 + tid] + bp[512 + tid] + bp[768 + tid];
    }
}

// ---------------------------------------------------------------------------
extern "C" void kernel_launch(void* const* d_in, const int* in_sizes, int n_in,
                              void* d_out, int out_size, void* d_ws, size_t ws_size,
                              hipStream_t stream) {
    const float* x   = (const float*)d_in[0];
    // d_in[1] = output_size (fixed 1024)
    const float* W1  = (const float*)d_in[2];
    const float* b1  = (const float*)d_in[3];
    const float* W2  = (const float*)d_in[4];
    const float* b2  = (const float*)d_in[5];
    const float* Wb1 = (const float*)d_in[6];
    const float* bb1 = (const float*)d_in[7];
    const float* Wb2 = (const float*)d_in[8];
    const float* bb2 = (const float*)d_in[9];
    float* out = (float*)d_out;

    float* v   = (float*)d_ws;       // B*H
    float* S   = v + B * H;          // B
    float* PA  = S + B;              // 32*H
    float* PY  = PA + 32 * H;        // 32*H
    float* HPE = PY + 32 * H;        // 32*H  (total 164 KB; ws is 256 MiB)

    hipLaunchKernelGGL(k0_tables, dim3(96),    dim3(256),  0, stream,
                       W1, b1, Wb1, bb1, PA, PY, HPE);
    hipLaunchKernelGGL(k1_v,      dim3(B * 4), dim3(1024), 0, stream,
                       x, W1, PA, PY, v, S);
    hipLaunchKernelGGL(k2_out,    dim3(256),   dim3(1024), 0, stream,
                       v, S, W2, b2, Wb1, HPE, Wb2, bb2, out);
}